// Round 12
// baseline (1784.017 us; speedup 1.0000x reference)
//
#include <hip/hip_runtime.h>
#include <hip/hip_bf16.h>

// GRU-GAN generator, MI355X. Round 12 — lean wave set, fewer DS ops.
// B=512, H=64, S=2048, F=32. 32 blocks x 640 threads (10 waves).
// Block = 16 batch rows (M=16 MFMA tile, transposed D[j][m] layout).
//   waves 0-7: gates (dir=w>>2, cb=w&3) — identical to R11 (pinned frags,
//              merged-rcp elementwise, gh carried across b2 in registers).
//   waves 8-9: latent x2 col-tiles each (W2) + out-proj f-tile (W1, riding
//              their formerly-idle window) + y store.
// R12 rationale: R8/R9/R11 all ~1750 cy/step with wildly different wave
// structures — the invariant is DS-pipe traffic (~52 ds_read_b128/step
// ~650cy on the one shared pipe) and 16 barrier arrivals. This round:
// 44 reads (latent 16->8: 2 waves read full h once for 2 tiles; outproj
// waves gone), 10 arrivals, no idle waves.
// Exactly 2 bar_lds per step on every path.

#define NBATCH 512
#define NH 64
#define NS 2048
#define NF 32
#define MROW 16
#define LDH 72    // padded LDS row stride (shorts): 144 B

typedef short s16x8 __attribute__((ext_vector_type(8)));
typedef float f32x4 __attribute__((ext_vector_type(4)));

#define MFMA(a, b, c) __builtin_amdgcn_mfma_f32_16x16x32_bf16((a), (b), (c), 0, 0, 0)

#define NLOG2E  (-1.4426950408889634f)
#define N2LOG2E (-2.8853900817779268f)

// pin a value in VGPRs: opaque to rematerialization
#define PIN(x) __asm__("" : "+v"(x))

// barrier that waits only on LDS (no vmcnt drain like __syncthreads)
__device__ __forceinline__ void bar_lds() {
    __asm__ volatile("s_waitcnt lgkmcnt(0)\n\ts_barrier" ::: "memory");
}

__device__ __forceinline__ short f2bf(float f) {
    return (short)((__float_as_uint(f) + 0x8000u) >> 16);
}

__device__ __forceinline__ f32x4 v_exp2(f32x4 a) {
    f32x4 r;
#pragma unroll
    for (int i = 0; i < 4; ++i) r[i] = __builtin_amdgcn_exp2f(a[i]);
    return r;
}

__device__ __forceinline__ f32x4 v_rcp(f32x4 a) {
    f32x4 r;
#pragma unroll
    for (int i = 0; i < 4; ++i) r[i] = __builtin_amdgcn_rcpf(a[i]);
    return r;
}

__device__ __forceinline__ f32x4 v_lk(f32x4 a) {
    f32x4 b = a * 0.01f;
    f32x4 r;
#pragma unroll
    for (int i = 0; i < 4; ++i) r[i] = fmaxf(a[i], b[i]);
    return r;
}

__device__ __forceinline__ f32x4 v_sigm(f32x4 a) {
    return v_rcp(v_exp2(a * NLOG2E) + 1.0f);
}

__device__ __forceinline__ int2 pk4bf(f32x4 v) {
    union { __hip_bfloat162 b; int i; } lo, hi;
    float2 a; a.x = v[0]; a.y = v[1];
    float2 b; b.x = v[2]; b.y = v[3];
    lo.b = __float22bfloat162_rn(a);
    hi.b = __float22bfloat162_rn(b);
    int2 r; r.x = lo.i; r.y = hi.i;
    return r;
}

__device__ __forceinline__ s16x8 bfragW(const float* __restrict__ W, int ldk,
                                        int row, int kf, int quad) {
    const float* p = W + (size_t)row * ldk + kf * 32 + quad * 8;
    s16x8 r;
#pragma unroll
    for (int i = 0; i < 8; ++i) r[i] = f2bf(p[i]);
    return r;
}

__device__ __forceinline__ f32x4 bias4(const float* __restrict__ p) {
    const float4 v = *(const float4*)p;
    f32x4 r = {v.x, v.y, v.z, v.w};
    return r;
}

__global__ __launch_bounds__(640)
__attribute__((amdgpu_waves_per_eu(3, 3)))
void grugan_kernel(const float* __restrict__ noise,
                   const float* __restrict__ Wihf, const float* __restrict__ Whhf,
                   const float* __restrict__ bihf, const float* __restrict__ bhhf,
                   const float* __restrict__ Wihb, const float* __restrict__ Whhb,
                   const float* __restrict__ bihb, const float* __restrict__ bhhb,
                   const float* __restrict__ Wlat, const float* __restrict__ blat,
                   const float* __restrict__ Wout, const float* __restrict__ bout,
                   float* __restrict__ out)
{
    __shared__ __align__(16) short Xs[2][MROW][LDH];
    __shared__ __align__(16) short X2s[2][MROW][LDH];
    __shared__ __align__(16) short Hs[2][2][MROW][LDH];

    const int tid  = threadIdx.x;
    const int wave = tid >> 6;
    const int lane = tid & 63;
    const int n    = lane & 15;   // batch row within tile
    const int quad = lane >> 4;
    const int row0 = blockIdx.x * MROW;

    // zero x(0); init h(0)
    for (int idx = tid; idx < MROW * LDH; idx += 640) (&Xs[0][0][0])[idx] = 0;
    f32x4 hreg = {0.f, 0.f, 0.f, 0.f};
    const int gdir = wave >> 2;             // valid for waves 0-7
    const int gjq  = (wave & 3) * 16 + quad * 4;
    if (wave < 8) {
        const float4 nz = *(const float4*)&noise[(size_t)(row0 + n) * NH + gjq];
        hreg[0] = nz.x; hreg[1] = nz.y; hreg[2] = nz.z; hreg[3] = nz.w;
        *(int2*)&Hs[0][gdir][n][gjq] = pk4bf(hreg);
    }
    __syncthreads();

    if (wave < 8) {
        // ======================= GATE WAVES (as R11) =======================
        const int dir  = gdir;
        const int cb   = wave & 3;
        const int jrow = cb * 16 + n;
        const int jq   = gjq;
        const float* Wih = dir ? Wihb : Wihf;
        const float* Whh = dir ? Whhb : Whhf;
        const float* bih = dir ? bihb : bihf;
        const float* bhh = dir ? bhhb : bhhf;

        s16x8 wir0 = bfragW(Wih, NH,   0 + jrow, 0, quad);
        s16x8 wir1 = bfragW(Wih, NH,   0 + jrow, 1, quad);
        s16x8 wiz0 = bfragW(Wih, NH,  64 + jrow, 0, quad);
        s16x8 wiz1 = bfragW(Wih, NH,  64 + jrow, 1, quad);
        s16x8 win0 = bfragW(Wih, NH, 128 + jrow, 0, quad);
        s16x8 win1 = bfragW(Wih, NH, 128 + jrow, 1, quad);
        s16x8 whr0 = bfragW(Whh, NH,   0 + jrow, 0, quad);
        s16x8 whr1 = bfragW(Whh, NH,   0 + jrow, 1, quad);
        s16x8 whz0 = bfragW(Whh, NH,  64 + jrow, 0, quad);
        s16x8 whz1 = bfragW(Whh, NH,  64 + jrow, 1, quad);
        s16x8 whn0 = bfragW(Whh, NH, 128 + jrow, 0, quad);
        s16x8 whn1 = bfragW(Whh, NH, 128 + jrow, 1, quad);
        f32x4 initR, initZ;
        {
            f32x4 a = bias4(&bih[jq]),      b = bias4(&bhh[jq]);
            initR = a + b;
            f32x4 c = bias4(&bih[64 + jq]), d = bias4(&bhh[64 + jq]);
            initZ = c + d;
        }
        f32x4 initN1 = bias4(&bih[128 + jq]);
        f32x4 initN2 = bias4(&bhh[128 + jq]);
        PIN(wir0); PIN(wir1); PIN(wiz0); PIN(wiz1); PIN(win0); PIN(win1);
        PIN(whr0); PIN(whr1); PIN(whz0); PIN(whz1); PIN(whn0); PIN(whn1);
        PIN(initR); PIN(initZ); PIN(initN1); PIN(initN2);

        f32x4 accR, accZ, accN2;
        {
            s16x8 ha0 = *(const s16x8*)&Hs[0][dir][n][quad * 8];
            s16x8 ha1 = *(const s16x8*)&Hs[0][dir][n][32 + quad * 8];
            accR  = MFMA(whr0, ha0, initR);  accR  = MFMA(whr1, ha1, accR);
            accZ  = MFMA(whz0, ha0, initZ);  accZ  = MFMA(whz1, ha1, accZ);
            accN2 = MFMA(whn0, ha0, initN2); accN2 = MFMA(whn1, ha1, accN2);
        }

#define GSTEP(HB) do {                                                          \
        s16x8 xa0 = *(const s16x8*)&Xs[HB][n][quad * 8];                        \
        s16x8 xa1 = *(const s16x8*)&Xs[HB][n][32 + quad * 8];                   \
        accR = MFMA(wir0, xa0, accR);   accR = MFMA(wir1, xa1, accR);           \
        accZ = MFMA(wiz0, xa0, accZ);   accZ = MFMA(wiz1, xa1, accZ);           \
        f32x4 accN1 = MFMA(win0, xa0, initN1);                                  \
        accN1 = MFMA(win1, xa1, accN1);                                         \
        f32x4 eR = v_exp2(accR * NLOG2E);                                       \
        f32x4 rr = v_rcp(eR + 1.0f);                                            \
        f32x4 u  = accN1 + rr * accN2;                                          \
        f32x4 eU = v_exp2(u * N2LOG2E);                                         \
        f32x4 eZ = v_exp2(accZ * NLOG2E);                                       \
        f32x4 numer = (eZ + hreg) + eU * (hreg - eZ);                           \
        f32x4 denom = (eU + 1.0f) * (eZ + 1.0f);                                \
        hreg = numer * v_rcp(denom);                                            \
        *(int2*)&Hs[(HB) ^ 1][dir][n][jq] = pk4bf(hreg);                        \
        bar_lds();  /* b1: H(t+1) visible */                                    \
        {                                                                       \
            s16x8 ha0 = *(const s16x8*)&Hs[(HB) ^ 1][dir][n][quad * 8];         \
            s16x8 ha1 = *(const s16x8*)&Hs[(HB) ^ 1][dir][n][32 + quad * 8];    \
            accR  = MFMA(whr0, ha0, initR);  accR  = MFMA(whr1, ha1, accR);     \
            accZ  = MFMA(whz0, ha0, initZ);  accZ  = MFMA(whz1, ha1, accZ);     \
            accN2 = MFMA(whn0, ha0, initN2); accN2 = MFMA(whn1, ha1, accN2);    \
        }                                                                       \
        bar_lds();  /* b2: x(t+1) visible */                                    \
    } while (0)

        for (int t = 0; t < NS; t += 2) {
            GSTEP(0);
            GSTEP(1);
        }
#undef GSTEP
    } else {
        // ============ LATENT + OUT-PROJ WAVES (waves 8,9) ============
        const int lw  = wave - 8;            // 0 or 1
        const int lt0 = lw * 2;              // col-tiles lt0, lt0+1
        const int nq0 = lt0 * 16 + quad * 4;
        const int nq1 = nq0 + 16;
        s16x8 wlA0 = bfragW(Wlat, 2 * NH, lt0 * 16 + n, 0, quad);
        s16x8 wlA1 = bfragW(Wlat, 2 * NH, lt0 * 16 + n, 1, quad);
        s16x8 wlA2 = bfragW(Wlat, 2 * NH, lt0 * 16 + n, 2, quad);
        s16x8 wlA3 = bfragW(Wlat, 2 * NH, lt0 * 16 + n, 3, quad);
        s16x8 wlB0 = bfragW(Wlat, 2 * NH, lt0 * 16 + 16 + n, 0, quad);
        s16x8 wlB1 = bfragW(Wlat, 2 * NH, lt0 * 16 + 16 + n, 1, quad);
        s16x8 wlB2 = bfragW(Wlat, 2 * NH, lt0 * 16 + 16 + n, 2, quad);
        s16x8 wlB3 = bfragW(Wlat, 2 * NH, lt0 * 16 + 16 + n, 3, quad);
        f32x4 initL0 = bias4(&blat[lt0 * 16 + quad * 4]);
        f32x4 initL1 = bias4(&blat[lt0 * 16 + 16 + quad * 4]);
        const int f0 = lw * 16;
        s16x8 wo0 = bfragW(Wout, NH, f0 + n, 0, quad);
        s16x8 wo1 = bfragW(Wout, NH, f0 + n, 1, quad);
        f32x4 initO = bias4(&bout[f0 + quad * 4]);
        PIN(wlA0); PIN(wlA1); PIN(wlA2); PIN(wlA3);
        PIN(wlB0); PIN(wlB1); PIN(wlB2); PIN(wlB3);
        PIN(initL0); PIN(initL1); PIN(wo0); PIN(wo1); PIN(initO);
        const f32x4 Z4 = {0.f, 0.f, 0.f, 0.f};
        float* const orow = out + (size_t)(row0 + n) * (NS * NF) + f0 + quad * 4;

#define LSTEP(HB, T) do {                                                       \
        /* W1 (rides otherwise-idle window): out-proj of ys[T-1] */             \
        if ((T) >= 1) {                                                         \
            s16x8 p0 = *(const s16x8*)&X2s[HB][n][quad * 8];                    \
            s16x8 p1 = *(const s16x8*)&X2s[HB][n][32 + quad * 8];               \
            f32x4 po = MFMA(wo0, p0, initO);                                    \
            po = MFMA(wo1, p1, po);                                             \
            *(f32x4*)(orow + (size_t)((T) - 1) * NF) = v_sigm(po);              \
        }                                                                       \
        bar_lds();  /* b1: H(t+1) visible */                                    \
        {                                                                       \
            s16x8 fa0 = *(const s16x8*)&Hs[(HB) ^ 1][0][n][quad * 8];           \
            s16x8 fa1 = *(const s16x8*)&Hs[(HB) ^ 1][0][n][32 + quad * 8];      \
            s16x8 ba0 = *(const s16x8*)&Hs[(HB) ^ 1][1][n][quad * 8];           \
            s16x8 ba1 = *(const s16x8*)&Hs[(HB) ^ 1][1][n][32 + quad * 8];      \
            f32x4 c1 = MFMA(wlA0, fa0, initL0);                                 \
            c1 = MFMA(wlA1, fa1, c1);                                           \
            f32x4 c2 = MFMA(wlA2, ba0, Z4);                                     \
            c2 = MFMA(wlA3, ba1, c2);                                           \
            f32x4 c3 = MFMA(wlB0, fa0, initL1);                                 \
            c3 = MFMA(wlB1, fa1, c3);                                           \
            f32x4 c4 = MFMA(wlB2, ba0, Z4);                                     \
            c4 = MFMA(wlB3, ba1, c4);                                           \
            f32x4 la0 = v_lk(c1 + c2);                                          \
            f32x4 la1 = v_lk(c3 + c4);                                          \
            *(int2*)&Xs[(HB) ^ 1][n][nq0]  = pk4bf(la0);                        \
            *(int2*)&X2s[(HB) ^ 1][n][nq0] = pk4bf(v_lk(la0));                  \
            *(int2*)&Xs[(HB) ^ 1][n][nq1]  = pk4bf(la1);                        \
            *(int2*)&X2s[(HB) ^ 1][n][nq1] = pk4bf(v_lk(la1));                  \
        }                                                                       \
        bar_lds();  /* b2: x(t+1) visible */                                    \
    } while (0)

        for (int t = 0; t < NS; t += 2) {
            LSTEP(0, t);
            LSTEP(1, t + 1);
        }
#undef LSTEP

        // epilogue: y(NS-1) from X2s[0] (= lk(ys[NS-1]), written at t=NS-1)
        s16x8 p0 = *(const s16x8*)&X2s[0][n][quad * 8];
        s16x8 p1 = *(const s16x8*)&X2s[0][n][32 + quad * 8];
        f32x4 po = MFMA(wo0, p0, initO);
        po = MFMA(wo1, p1, po);
        *(f32x4*)(orow + (size_t)(NS - 1) * NF) = v_sigm(po);
    }
}

extern "C" void kernel_launch(void* const* d_in, const int* in_sizes, int n_in,
                              void* d_out, int out_size, void* d_ws, size_t ws_size,
                              hipStream_t stream) {
    const float* noise = (const float*)d_in[0];
    const float* Wihf  = (const float*)d_in[1];
    const float* Whhf  = (const float*)d_in[2];
    const float* bihf  = (const float*)d_in[3];
    const float* bhhf  = (const float*)d_in[4];
    const float* Wihb  = (const float*)d_in[5];
    const float* Whhb  = (const float*)d_in[6];
    const float* bihb  = (const float*)d_in[7];
    const float* bhhb  = (const float*)d_in[8];
    const float* Wlat  = (const float*)d_in[9];
    const float* blat  = (const float*)d_in[10];
    const float* Wout  = (const float*)d_in[11];
    const float* bout  = (const float*)d_in[12];

    grugan_kernel<<<dim3(NBATCH / MROW), dim3(640), 0, stream>>>(
        noise, Wihf, Whhf, bihf, bhhf, Wihb, Whhb, bihb, bhhb,
        Wlat, blat, Wout, bout, (float*)d_out);
}